// Round 1
// baseline (8515.002 us; speedup 1.0000x reference)
//
#include <hip/hip_runtime.h>
#include <math.h>

#define NPIX 1600
#define NIMG 40

__device__ __forceinline__ float2 cmul(float2 a, float2 b) {
    return make_float2(a.x * b.x - a.y * b.y, a.x * b.y + a.y * b.x);
}

// One block per (b,c) image. fft2 / ifft2 with ortho norm via two 40x40
// complex matmuls in LDS. dir = -1 forward, +1 inverse.
// D is symmetric (D[v][w] = tw[(v*w)%40]), so row pass reads D[w*40+v]
// (lane-consecutive, conflict-free) instead of D[v*40+w] (16-way conflict).
template<bool REAL_IN, bool RELU, bool REAL_OUT>
__global__ __launch_bounds__(256) void fft2_kernel(const void* __restrict__ inv,
                                                   void* __restrict__ outv,
                                                   int dir)
{
    const int img = blockIdx.x;
    const int tid = threadIdx.x;
    __shared__ float2 A[NPIX];
    __shared__ float2 T[NPIX];
    __shared__ float2 D[NPIX];
    __shared__ float2 tw[NIMG];

    if (tid < NIMG) {
        float ang = (float)dir * 6.28318530717958647692f * (float)tid / 40.0f;
        float s, c;
        sincosf(ang, &s, &c);
        tw[tid] = make_float2(c, s);  // e^{i*dir*2pi*k/40}
    }
    if (REAL_IN) {
        const float* in = (const float*)inv + (size_t)img * NPIX;
        for (int idx = tid; idx < NPIX; idx += 256)
            A[idx] = make_float2(in[idx], 0.0f);
    } else {
        const float2* in = (const float2*)inv + (size_t)img * NPIX;
        for (int idx = tid; idx < NPIX; idx += 256)
            A[idx] = in[idx];
    }
    __syncthreads();
    for (int idx = tid; idx < NPIX; idx += 256) {
        int a = idx / NIMG, b = idx - a * NIMG;
        D[idx] = tw[(a * b) % NIMG];
    }
    __syncthreads();

    // Row pass: T[h][v] = sum_w A[h][w] * D[v][w]  (use D[w][v], symmetric)
    for (int idx = tid; idx < NPIX; idx += 256) {
        int h = idx / NIMG, v = idx - h * NIMG;
        float2 s = make_float2(0.0f, 0.0f);
        const float2* Arow = &A[h * NIMG];
        #pragma unroll
        for (int w = 0; w < NIMG; ++w) {
            float2 a = Arow[w];          // broadcast within lane-group (h fixed)
            float2 d = D[w * NIMG + v];  // lane-consecutive in v
            s.x += a.x * d.x - a.y * d.y;
            s.y += a.x * d.y + a.y * d.x;
        }
        T[idx] = s;  // idx == h*40 + v
    }
    __syncthreads();

    // Col pass: F[u][v] = (1/40) sum_h T[h][v] * D[u][h]
    for (int idx = tid; idx < NPIX; idx += 256) {
        int u = idx / NIMG, v = idx - u * NIMG;
        float2 s = make_float2(0.0f, 0.0f);
        const float2* Du = &D[u * NIMG];
        #pragma unroll
        for (int h = 0; h < NIMG; ++h) {
            float2 t = T[h * NIMG + v];  // lane-consecutive in v
            float2 d = Du[h];            // broadcast (u fixed per lane-group)
            s.x += t.x * d.x - t.y * d.y;
            s.y += t.x * d.y + t.y * d.x;
        }
        s.x *= 0.025f;  // ortho: 1/sqrt(40*40)
        s.y *= 0.025f;
        if (RELU) { s.x = fmaxf(s.x, 0.0f); s.y = fmaxf(s.y, 0.0f); }
        if (REAL_OUT) {
            ((float*)outv)[(size_t)img * NPIX + idx] = s.x;
        } else {
            ((float2*)outv)[(size_t)img * NPIX + idx] = s;
        }
    }
}

// Per-frequency channel mix: M[b][o][f] = sum_i F[b][i][f] * W[i][o][f]
// Block = 256 threads = 64 f-lanes x 4 batches; acc[OUTC] held in VGPRs.
// F read exactly once; W streamed (L2/L3-resident, 20.5 MB/layer).
template<int INC, int OUTC>
__global__ __launch_bounds__(256) void mix_kernel(const float2* __restrict__ F,
                                                  const float2* __restrict__ W,
                                                  float2* __restrict__ M)
{
    const int tid = threadIdx.x;
    const int lane = tid & 63;
    const int brow = tid >> 6;
    const int fchunk = blockIdx.x % 25;
    const int btile = blockIdx.x / 25;
    const int f = fchunk * 64 + lane;
    const int b = btile * 4 + brow;

    float2 acc[OUTC];
    #pragma unroll
    for (int o = 0; o < OUTC; ++o) acc[o] = make_float2(0.0f, 0.0f);

    for (int i = 0; i < INC; ++i) {
        float2 fv = F[((size_t)b * INC + i) * NPIX + f];
        #pragma unroll
        for (int o = 0; o < OUTC; ++o) {
            float2 w = W[((size_t)i * OUTC + o) * NPIX + f];
            acc[o].x += fv.x * w.x - fv.y * w.y;
            acc[o].y += fv.x * w.y + fv.y * w.x;
        }
    }
    #pragma unroll
    for (int o = 0; o < OUTC; ++o)
        M[((size_t)b * OUTC + o) * NPIX + f] = acc[o];
}

extern "C" void kernel_launch(void* const* d_in, const int* in_sizes, int n_in,
                              void* d_out, int out_size, void* d_ws, size_t ws_size,
                              hipStream_t stream)
{
    const float* x = (const float*)d_in[0];
    const float2* w[6];
    for (int i = 0; i < 6; ++i) w[i] = (const float2*)d_in[1 + i];
    float* out = (float*)d_out;

    const size_t bufBytes = (size_t)256 * 40 * NPIX * sizeof(float2);  // 131 MB
    float2* A = (float2*)d_ws;
    float2* B = (float2*)((char*)d_ws + bufBytes);

    const int BIG = 256 * 40;  // 10240 images

    // Layer 1: x (real, 1 chan) -> fft -> mix(1->40) -> ifft+relu
    fft2_kernel<true, false, false><<<256, 256, 0, stream>>>(x, A, -1);
    mix_kernel<1, 40><<<1600, 256, 0, stream>>>(A, w[0], B);
    fft2_kernel<false, true, false><<<BIG, 256, 0, stream>>>(B, A, +1);

    // Layers 2..5: fft -> mix(40->40) -> ifft+relu, ping-pong A/B
    float2* P = A;
    float2* Q = B;
    for (int l = 1; l <= 4; ++l) {
        fft2_kernel<false, false, false><<<BIG, 256, 0, stream>>>(P, Q, -1);
        mix_kernel<40, 40><<<1600, 256, 0, stream>>>(Q, w[l], P);
        fft2_kernel<false, true, false><<<BIG, 256, 0, stream>>>(P, Q, +1);
        float2* t = P; P = Q; Q = t;
    }

    // Layer 6: fft -> mix(40->1) -> ifft, write real part only
    fft2_kernel<false, false, false><<<BIG, 256, 0, stream>>>(P, Q, -1);
    mix_kernel<40, 1><<<1600, 256, 0, stream>>>(Q, w[5], P);
    fft2_kernel<false, false, true><<<256, 256, 0, stream>>>(P, out, +1);
}

// Round 2
// 5417.843 us; speedup vs baseline: 1.5717x; 1.5717x over previous
//
#include <hip/hip_runtime.h>
#include <math.h>

#define NPIX 1600
#define NIMG 40

// One block per (b,c) image. fft2 / ifft2 with ortho norm via two 40x40
// complex matmuls in LDS. dir = -1 forward, +1 inverse.
// D is symmetric (D[v][w] = tw[(v*w)%40]), so row pass reads D[w*40+v]
// (lane-consecutive, conflict-free) instead of D[v*40+w] (16-way conflict).
template<bool REAL_IN, bool RELU, bool REAL_OUT>
__global__ __launch_bounds__(256) void fft2_kernel(const void* __restrict__ inv,
                                                   void* __restrict__ outv,
                                                   int dir)
{
    const int img = blockIdx.x;
    const int tid = threadIdx.x;
    __shared__ float2 A[NPIX];
    __shared__ float2 T[NPIX];
    __shared__ float2 D[NPIX];
    __shared__ float2 tw[NIMG];

    if (tid < NIMG) {
        float ang = (float)dir * 6.28318530717958647692f * (float)tid / 40.0f;
        float s, c;
        sincosf(ang, &s, &c);
        tw[tid] = make_float2(c, s);  // e^{i*dir*2pi*k/40}
    }
    if (REAL_IN) {
        const float* in = (const float*)inv + (size_t)img * NPIX;
        for (int idx = tid; idx < NPIX; idx += 256)
            A[idx] = make_float2(in[idx], 0.0f);
    } else {
        const float2* in = (const float2*)inv + (size_t)img * NPIX;
        for (int idx = tid; idx < NPIX; idx += 256)
            A[idx] = in[idx];
    }
    __syncthreads();
    for (int idx = tid; idx < NPIX; idx += 256) {
        int a = idx / NIMG, b = idx - a * NIMG;
        D[idx] = tw[(a * b) % NIMG];
    }
    __syncthreads();

    // Row pass: T[h][v] = sum_w A[h][w] * D[v][w]  (use D[w][v], symmetric)
    for (int idx = tid; idx < NPIX; idx += 256) {
        int h = idx / NIMG, v = idx - h * NIMG;
        float2 s = make_float2(0.0f, 0.0f);
        const float2* Arow = &A[h * NIMG];
        #pragma unroll
        for (int w = 0; w < NIMG; ++w) {
            float2 a = Arow[w];          // broadcast within lane-group (h fixed)
            float2 d = D[w * NIMG + v];  // lane-consecutive in v
            s.x += a.x * d.x - a.y * d.y;
            s.y += a.x * d.y + a.y * d.x;
        }
        T[idx] = s;  // idx == h*40 + v
    }
    __syncthreads();

    // Col pass: F[u][v] = (1/40) sum_h T[h][v] * D[u][h]
    for (int idx = tid; idx < NPIX; idx += 256) {
        int u = idx / NIMG, v = idx - u * NIMG;
        float2 s = make_float2(0.0f, 0.0f);
        const float2* Du = &D[u * NIMG];
        #pragma unroll
        for (int h = 0; h < NIMG; ++h) {
            float2 t = T[h * NIMG + v];  // lane-consecutive in v
            float2 d = Du[h];            // broadcast (u fixed per lane-group)
            s.x += t.x * d.x - t.y * d.y;
            s.y += t.x * d.y + t.y * d.x;
        }
        s.x *= 0.025f;  // ortho: 1/sqrt(40*40)
        s.y *= 0.025f;
        if (RELU) { s.x = fmaxf(s.x, 0.0f); s.y = fmaxf(s.y, 0.0f); }
        if (REAL_OUT) {
            ((float*)outv)[(size_t)img * NPIX + idx] = s.x;
        } else {
            ((float2*)outv)[(size_t)img * NPIX + idx] = s;
        }
    }
}

// Per-frequency channel mix: M[b][o][f] = sum_i F[b][i][f] * W[i][o][f]
// Register-tiled: each thread owns BT batches x OT output channels per pass
// (OUTC/OT passes). acc = BT*OT*2 floats kept in VGPRs (BT=2,OT=10 -> 40).
// W aggregate cache traffic = 5.24/BT GB; F re-read OUTC/OT times (L2/L3).
// Block = 256 threads = 4 waves; each wave = 64 f-lanes x 1 batch-group.
template<int INC, int OUTC, int BT, int OT>
__global__ __launch_bounds__(256) void mix_kernel(const float2* __restrict__ F,
                                                  const float2* __restrict__ W,
                                                  float2* __restrict__ M)
{
    const int tid = threadIdx.x;
    const int lane = tid & 63;
    const int wv = tid >> 6;
    const int f = (blockIdx.x % 25) * 64 + lane;
    const int bg = (blockIdx.x / 25) * 4 + wv;   // batch-group index
    const int b0 = bg * BT;

    #pragma unroll
    for (int o0 = 0; o0 < OUTC; o0 += OT) {
        float2 acc[BT][OT];
        #pragma unroll
        for (int t = 0; t < BT; ++t)
            #pragma unroll
            for (int o = 0; o < OT; ++o)
                acc[t][o] = make_float2(0.0f, 0.0f);

        for (int i = 0; i < INC; ++i) {
            float2 fv[BT];
            #pragma unroll
            for (int t = 0; t < BT; ++t)
                fv[t] = F[((size_t)(b0 + t) * INC + i) * NPIX + f];
            float2 wr[OT];
            #pragma unroll
            for (int o = 0; o < OT; ++o)
                wr[o] = W[((size_t)i * OUTC + (o0 + o)) * NPIX + f];
            #pragma unroll
            for (int t = 0; t < BT; ++t)
                #pragma unroll
                for (int o = 0; o < OT; ++o) {
                    acc[t][o].x = fmaf(fv[t].x, wr[o].x,
                                  fmaf(-fv[t].y, wr[o].y, acc[t][o].x));
                    acc[t][o].y = fmaf(fv[t].x, wr[o].y,
                                  fmaf(fv[t].y, wr[o].x, acc[t][o].y));
                }
        }
        #pragma unroll
        for (int t = 0; t < BT; ++t)
            #pragma unroll
            for (int o = 0; o < OT; ++o)
                M[((size_t)(b0 + t) * OUTC + (o0 + o)) * NPIX + f] = acc[t][o];
    }
}

extern "C" void kernel_launch(void* const* d_in, const int* in_sizes, int n_in,
                              void* d_out, int out_size, void* d_ws, size_t ws_size,
                              hipStream_t stream)
{
    const float* x = (const float*)d_in[0];
    const float2* w[6];
    for (int i = 0; i < 6; ++i) w[i] = (const float2*)d_in[1 + i];
    float* out = (float*)d_out;

    const size_t bufBytes = (size_t)256 * 40 * NPIX * sizeof(float2);  // 131 MB
    float2* A = (float2*)d_ws;
    float2* B = (float2*)((char*)d_ws + bufBytes);

    const int BIG = 256 * 40;   // 10240 images
    const int MIXBLK = 25 * (256 / 2) / 4;  // 25 f-chunks * 128 bgroups / 4 per block = 800

    // Layer 1: x (real, 1 chan) -> fft -> mix(1->40) -> ifft+relu
    fft2_kernel<true, false, false><<<256, 256, 0, stream>>>(x, A, -1);
    mix_kernel<1, 40, 2, 10><<<MIXBLK, 256, 0, stream>>>(A, w[0], B);
    fft2_kernel<false, true, false><<<BIG, 256, 0, stream>>>(B, A, +1);

    // Layers 2..5: fft -> mix(40->40) -> ifft+relu, ping-pong A/B
    float2* P = A;
    float2* Q = B;
    for (int l = 1; l <= 4; ++l) {
        fft2_kernel<false, false, false><<<BIG, 256, 0, stream>>>(P, Q, -1);
        mix_kernel<40, 40, 2, 10><<<MIXBLK, 256, 0, stream>>>(Q, w[l], P);
        fft2_kernel<false, true, false><<<BIG, 256, 0, stream>>>(P, Q, +1);
        float2* t = P; P = Q; Q = t;
    }

    // Layer 6: fft -> mix(40->1) -> ifft, write real part only
    fft2_kernel<false, false, false><<<BIG, 256, 0, stream>>>(P, Q, -1);
    mix_kernel<40, 1, 2, 1><<<MIXBLK, 256, 0, stream>>>(Q, w[5], P);
    fft2_kernel<false, false, true><<<256, 256, 0, stream>>>(P, out, +1);
}

// Round 3
// 3116.167 us; speedup vs baseline: 2.7325x; 1.7386x over previous
//
#include <hip/hip_runtime.h>
#include <math.h>

#define NPIX 1600
#define NIMG 40

// ---------------------------------------------------------------------------
// Small-edge kernel (unchanged from R1, only 256-block dispatches x2):
// one block per (b,c) image, fft2/ifft2 with ortho norm via two 40x40 complex
// matmuls in LDS. dir = -1 forward, +1 inverse.
// ---------------------------------------------------------------------------
template<bool REAL_IN, bool RELU, bool REAL_OUT>
__global__ __launch_bounds__(256) void fft2_kernel(const void* __restrict__ inv,
                                                   void* __restrict__ outv,
                                                   int dir)
{
    const int img = blockIdx.x;
    const int tid = threadIdx.x;
    __shared__ float2 A[NPIX];
    __shared__ float2 T[NPIX];
    __shared__ float2 D[NPIX];
    __shared__ float2 tw[NIMG];

    if (tid < NIMG) {
        float ang = (float)dir * 6.28318530717958647692f * (float)tid / 40.0f;
        float s, c;
        sincosf(ang, &s, &c);
        tw[tid] = make_float2(c, s);
    }
    if (REAL_IN) {
        const float* in = (const float*)inv + (size_t)img * NPIX;
        for (int idx = tid; idx < NPIX; idx += 256)
            A[idx] = make_float2(in[idx], 0.0f);
    } else {
        const float2* in = (const float2*)inv + (size_t)img * NPIX;
        for (int idx = tid; idx < NPIX; idx += 256)
            A[idx] = in[idx];
    }
    __syncthreads();
    for (int idx = tid; idx < NPIX; idx += 256) {
        int a = idx / NIMG, b = idx - a * NIMG;
        D[idx] = tw[(a * b) % NIMG];
    }
    __syncthreads();

    for (int idx = tid; idx < NPIX; idx += 256) {
        int h = idx / NIMG, v = idx - h * NIMG;
        float2 s = make_float2(0.0f, 0.0f);
        const float2* Arow = &A[h * NIMG];
        #pragma unroll
        for (int w = 0; w < NIMG; ++w) {
            float2 a = Arow[w];
            float2 d = D[w * NIMG + v];
            s.x += a.x * d.x - a.y * d.y;
            s.y += a.x * d.y + a.y * d.x;
        }
        T[idx] = s;
    }
    __syncthreads();

    for (int idx = tid; idx < NPIX; idx += 256) {
        int u = idx / NIMG, v = idx - u * NIMG;
        float2 s = make_float2(0.0f, 0.0f);
        const float2* Du = &D[u * NIMG];
        #pragma unroll
        for (int h = 0; h < NIMG; ++h) {
            float2 t = T[h * NIMG + v];
            float2 d = Du[h];
            s.x += t.x * d.x - t.y * d.y;
            s.y += t.x * d.y + t.y * d.x;
        }
        s.x *= 0.025f;
        s.y *= 0.025f;
        if (RELU) { s.x = fmaxf(s.x, 0.0f); s.y = fmaxf(s.y, 0.0f); }
        if (REAL_OUT) {
            ((float*)outv)[(size_t)img * NPIX + idx] = s.x;
        } else {
            ((float2*)outv)[(size_t)img * NPIX + idx] = s;
        }
    }
}

// ---------------------------------------------------------------------------
// Fused ifft2 -> CReLU -> fft2, one image per block, 320 threads (5 waves).
// Thread owns v = tid%40 (fixed) and 5 outputs h = tid/40 + 8k. K-loop fully
// unrolled: every ds_read is base + immediate offset (no in-loop addr math).
// D built once for dir=+1 (ifft); forward fft uses conj via sgn=-1:
//   row pass:  conj applied to lane operand d (2 mults / 40 fma)
//   col pass:  conj(D)*T = conj(D*conj(T)) -> sign on t at load + on acc.y.
// Per w-pair per wave: 2 lane-b64 + 5 broadcast-b128 LDS vs 40 fma.
// LDS 38.7 KB -> 4 blocks/CU (20 waves).
// ---------------------------------------------------------------------------
__global__ __launch_bounds__(320) void fused_layer_kernel(const float2* __restrict__ in,
                                                          float2* __restrict__ outg)
{
    const int img = blockIdx.x;
    const int tid = threadIdx.x;
    __shared__ float2 A[NPIX];
    __shared__ float2 T[NPIX];
    __shared__ float2 D[NPIX];
    __shared__ float2 tw[NIMG];

    // Load image (coalesced) + twiddles
    {
        const float2* src = in + (size_t)img * NPIX;
        #pragma unroll
        for (int k = 0; k < 5; ++k)
            A[tid + 320 * k] = src[tid + 320 * k];
    }
    if (tid < NIMG) {
        float ang = 6.28318530717958647692f * (float)tid / 40.0f;
        float s, c;
        sincosf(ang, &s, &c);
        tw[tid] = make_float2(c, s);  // e^{+i 2pi t/40}  (ifft direction)
    }
    __syncthreads();
    #pragma unroll
    for (int k = 0; k < 5; ++k) {
        int idx = tid + 320 * k;
        int a = idx / NIMG, b = idx - a * NIMG;
        D[idx] = tw[(a * b) % NIMG];
    }
    __syncthreads();

    const int v  = tid % NIMG;   // fixed per thread
    const int r0 = tid / NIMG;   // 0..7; outputs at r0 + 8k, k=0..4

    for (int rep = 0; rep < 2; ++rep) {        // rep0 = ifft(+relu), rep1 = fft
        const float sgn = rep ? -1.0f : 1.0f;

        // Row pass: T[h][v] = sum_w A[h][w] * D^(sgn)[w][v]
        {
            float2 acc[5];
            #pragma unroll
            for (int k = 0; k < 5; ++k) acc[k] = make_float2(0.0f, 0.0f);

            #pragma unroll
            for (int w = 0; w < NIMG; w += 2) {
                float2 d0 = D[w * NIMG + v];
                float2 d1 = D[(w + 1) * NIMG + v];
                d0.y *= sgn;
                d1.y *= sgn;
                #pragma unroll
                for (int k = 0; k < 5; ++k) {
                    const int h = r0 + 8 * k;
                    float4 ap = *(const float4*)&A[h * NIMG + w];  // A[h][w], A[h][w+1]
                    acc[k].x = fmaf(ap.x, d0.x, fmaf(-ap.y, d0.y, acc[k].x));
                    acc[k].y = fmaf(ap.x, d0.y, fmaf(ap.y, d0.x, acc[k].y));
                    acc[k].x = fmaf(ap.z, d1.x, fmaf(-ap.w, d1.y, acc[k].x));
                    acc[k].y = fmaf(ap.z, d1.y, fmaf(ap.w, d1.x, acc[k].y));
                }
            }
            #pragma unroll
            for (int k = 0; k < 5; ++k)
                T[(r0 + 8 * k) * NIMG + v] = acc[k];
        }
        __syncthreads();

        // Col pass: A[u][v] = 0.025 * sum_h D^(sgn)[u][h] * T[h][v]
        {
            float2 acc[5];
            #pragma unroll
            for (int k = 0; k < 5; ++k) acc[k] = make_float2(0.0f, 0.0f);

            #pragma unroll
            for (int h = 0; h < NIMG; h += 2) {
                float2 t0 = T[h * NIMG + v];
                float2 t1 = T[(h + 1) * NIMG + v];
                t0.y *= sgn;   // conj(T) when sgn=-1
                t1.y *= sgn;
                #pragma unroll
                for (int k = 0; k < 5; ++k) {
                    const int u = r0 + 8 * k;
                    float4 dp = *(const float4*)&D[u * NIMG + h];  // D[u][h], D[u][h+1]
                    acc[k].x = fmaf(dp.x, t0.x, fmaf(-dp.y, t0.y, acc[k].x));
                    acc[k].y = fmaf(dp.x, t0.y, fmaf(dp.y, t0.x, acc[k].y));
                    acc[k].x = fmaf(dp.z, t1.x, fmaf(-dp.w, t1.y, acc[k].x));
                    acc[k].y = fmaf(dp.z, t1.y, fmaf(dp.w, t1.x, acc[k].y));
                }
            }
            #pragma unroll
            for (int k = 0; k < 5; ++k) {
                float2 s;
                s.x = acc[k].x * 0.025f;
                s.y = acc[k].y * 0.025f * sgn;   // undo conj
                if (rep == 0) { s.x = fmaxf(s.x, 0.0f); s.y = fmaxf(s.y, 0.0f); }
                A[(r0 + 8 * k) * NIMG + v] = s;
            }
        }
        __syncthreads();
    }

    // Store spectral output (coalesced)
    {
        float2* dst = outg + (size_t)img * NPIX;
        #pragma unroll
        for (int k = 0; k < 5; ++k)
            dst[tid + 320 * k] = A[tid + 320 * k];
    }
}

// ---------------------------------------------------------------------------
// Per-frequency channel mix (unchanged from R1): each thread BT batches x OT
// output channels per pass; acc in VGPRs.
// ---------------------------------------------------------------------------
template<int INC, int OUTC, int BT, int OT>
__global__ __launch_bounds__(256) void mix_kernel(const float2* __restrict__ F,
                                                  const float2* __restrict__ W,
                                                  float2* __restrict__ M)
{
    const int tid = threadIdx.x;
    const int lane = tid & 63;
    const int wv = tid >> 6;
    const int f = (blockIdx.x % 25) * 64 + lane;
    const int bg = (blockIdx.x / 25) * 4 + wv;
    const int b0 = bg * BT;

    #pragma unroll
    for (int o0 = 0; o0 < OUTC; o0 += OT) {
        float2 acc[BT][OT];
        #pragma unroll
        for (int t = 0; t < BT; ++t)
            #pragma unroll
            for (int o = 0; o < OT; ++o)
                acc[t][o] = make_float2(0.0f, 0.0f);

        for (int i = 0; i < INC; ++i) {
            float2 fv[BT];
            #pragma unroll
            for (int t = 0; t < BT; ++t)
                fv[t] = F[((size_t)(b0 + t) * INC + i) * NPIX + f];
            float2 wr[OT];
            #pragma unroll
            for (int o = 0; o < OT; ++o)
                wr[o] = W[((size_t)i * OUTC + (o0 + o)) * NPIX + f];
            #pragma unroll
            for (int t = 0; t < BT; ++t)
                #pragma unroll
                for (int o = 0; o < OT; ++o) {
                    acc[t][o].x = fmaf(fv[t].x, wr[o].x,
                                  fmaf(-fv[t].y, wr[o].y, acc[t][o].x));
                    acc[t][o].y = fmaf(fv[t].x, wr[o].y,
                                  fmaf(fv[t].y, wr[o].x, acc[t][o].y));
                }
        }
        #pragma unroll
        for (int t = 0; t < BT; ++t)
            #pragma unroll
            for (int o = 0; o < OT; ++o)
                M[((size_t)(b0 + t) * OUTC + (o0 + o)) * NPIX + f] = acc[t][o];
    }
}

extern "C" void kernel_launch(void* const* d_in, const int* in_sizes, int n_in,
                              void* d_out, int out_size, void* d_ws, size_t ws_size,
                              hipStream_t stream)
{
    const float* x = (const float*)d_in[0];
    const float2* w[6];
    for (int i = 0; i < 6; ++i) w[i] = (const float2*)d_in[1 + i];
    float* out = (float*)d_out;

    const size_t bufBytes = (size_t)256 * 40 * NPIX * sizeof(float2);  // 131 MB
    float2* A = (float2*)d_ws;
    float2* B = (float2*)((char*)d_ws + bufBytes);

    const int BIG = 256 * 40;               // 10240 images
    const int MIXBLK = 25 * (256 / 2) / 4;  // 800

    // L1 head: fft(x) (small, 256 images)
    fft2_kernel<true, false, false><<<256, 256, 0, stream>>>(x, A, -1);

    // mix_l -> fused(ifft+relu+fft) for layers 1..5
    mix_kernel<1, 40, 2, 10><<<MIXBLK, 256, 0, stream>>>(A, w[0], B);
    fused_layer_kernel<<<BIG, 320, 0, stream>>>(B, A);
    for (int l = 1; l <= 4; ++l) {
        mix_kernel<40, 40, 2, 10><<<MIXBLK, 256, 0, stream>>>(A, w[l], B);
        fused_layer_kernel<<<BIG, 320, 0, stream>>>(B, A);
    }

    // L6: mix(40->1) then final ifft (small, 256 images), real output
    mix_kernel<40, 1, 2, 1><<<MIXBLK, 256, 0, stream>>>(A, w[5], B);
    fft2_kernel<false, false, true><<<256, 256, 0, stream>>>(B, out, +1);
}

// Round 4
// 2893.788 us; speedup vs baseline: 2.9425x; 1.0768x over previous
//
#include <hip/hip_runtime.h>
#include <math.h>

#define NPIX 1600
#define NIMG 40
#define IPB 4   // images per fused block

__device__ __forceinline__ void cfma(float2& acc, float ax, float ay, float dx, float dy) {
    // acc += (ax + i*ay) * (dx + i*dy)
    acc.x = fmaf(ax, dx, fmaf(-ay, dy, acc.x));
    acc.y = fmaf(ax, dy, fmaf( ay, dx, acc.y));
}

// ---------------------------------------------------------------------------
// Small-edge kernel (head/tail only, 256 blocks each): one block per (b,c)
// image, fft2/ifft2 ortho via two 40x40 complex matmuls in LDS.
// ---------------------------------------------------------------------------
template<bool REAL_IN, bool RELU, bool REAL_OUT>
__global__ __launch_bounds__(256) void fft2_kernel(const void* __restrict__ inv,
                                                   void* __restrict__ outv,
                                                   int dir)
{
    const int img = blockIdx.x;
    const int tid = threadIdx.x;
    __shared__ float2 A[NPIX];
    __shared__ float2 T[NPIX];
    __shared__ float2 D[NPIX];
    __shared__ float2 tw[NIMG];

    if (tid < NIMG) {
        float ang = (float)dir * 6.28318530717958647692f * (float)tid / 40.0f;
        float s, c;
        sincosf(ang, &s, &c);
        tw[tid] = make_float2(c, s);
    }
    if (REAL_IN) {
        const float* in = (const float*)inv + (size_t)img * NPIX;
        for (int idx = tid; idx < NPIX; idx += 256)
            A[idx] = make_float2(in[idx], 0.0f);
    } else {
        const float2* in = (const float2*)inv + (size_t)img * NPIX;
        for (int idx = tid; idx < NPIX; idx += 256)
            A[idx] = in[idx];
    }
    __syncthreads();
    for (int idx = tid; idx < NPIX; idx += 256) {
        int a = idx / NIMG, b = idx - a * NIMG;
        D[idx] = tw[(a * b) % NIMG];
    }
    __syncthreads();

    for (int idx = tid; idx < NPIX; idx += 256) {
        int h = idx / NIMG, v = idx - h * NIMG;
        float2 s = make_float2(0.0f, 0.0f);
        const float2* Arow = &A[h * NIMG];
        #pragma unroll
        for (int w = 0; w < NIMG; ++w) {
            float2 a = Arow[w];
            float2 d = D[w * NIMG + v];
            s.x += a.x * d.x - a.y * d.y;
            s.y += a.x * d.y + a.y * d.x;
        }
        T[idx] = s;
    }
    __syncthreads();

    for (int idx = tid; idx < NPIX; idx += 256) {
        int u = idx / NIMG, v = idx - u * NIMG;
        float2 s = make_float2(0.0f, 0.0f);
        const float2* Du = &D[u * NIMG];
        #pragma unroll
        for (int h = 0; h < NIMG; ++h) {
            float2 t = T[h * NIMG + v];
            float2 d = Du[h];
            s.x += t.x * d.x - t.y * d.y;
            s.y += t.x * d.y + t.y * d.x;
        }
        s.x *= 0.025f;
        s.y *= 0.025f;
        if (RELU) { s.x = fmaxf(s.x, 0.0f); s.y = fmaxf(s.y, 0.0f); }
        if (REAL_OUT) {
            ((float*)outv)[(size_t)img * NPIX + idx] = s.x;
        } else {
            ((float2*)outv)[(size_t)img * NPIX + idx] = s;
        }
    }
}

// ---------------------------------------------------------------------------
// Fused ifft2 -> CReLU -> fft2. 320 threads, IPB=4 images per block, in-place
// A (no T buffer: accumulate in regs, barrier, overwrite). Thread tile:
// 4 consecutive v (v0=4*(lo%10)) x 5 rows (h=r0+8k, r0=lo/10). Per w-pair
// iter: 9 ds_read_b128 per 40 cfma (R3: 7 per 10) -> LDS cyc/CU ~432k =
// 180us vs 133us VALU floor. LDS 63KB -> 2 blocks/CU (10 waves).
// Forward fft via conj trick on the shared ifft-direction D table.
// ---------------------------------------------------------------------------
__global__ __launch_bounds__(320) void fused_layer_kernel(const float2* __restrict__ in,
                                                          float2* __restrict__ outg)
{
    __shared__ float2 A[IPB * NPIX];
    __shared__ float2 D[NPIX];
    __shared__ float2 tw[NIMG];

    const int tid = threadIdx.x;
    const size_t base = (size_t)blockIdx.x * (IPB * NPIX);

    // Coalesced load: 4 images = 3200 float4
    {
        const float4* src = (const float4*)(in + base);
        float4* dst = (float4*)A;
        #pragma unroll
        for (int k = 0; k < 10; ++k)
            dst[tid + 320 * k] = src[tid + 320 * k];
    }
    if (tid < NIMG) {
        float ang = 6.28318530717958647692f * (float)tid / 40.0f;
        float s, c;
        sincosf(ang, &s, &c);
        tw[tid] = make_float2(c, s);  // ifft direction e^{+i 2pi t/40}
    }
    __syncthreads();
    #pragma unroll
    for (int k = 0; k < 5; ++k) {
        int idx = tid + 320 * k;
        int a = idx / NIMG, b = idx - a * NIMG;
        D[idx] = tw[(a * b) % NIMG];
    }
    __syncthreads();

    const int il = tid / 80;          // image within block
    const int lo = tid % 80;
    const int v0 = (lo % 10) * 4;     // owns v0..v0+3
    const int r0 = lo / 10;           // rows/cols r0+8k, k<5
    float2* Ai = &A[il * NPIX];

    float2 acc[5][4];

    for (int rep = 0; rep < 2; ++rep) {   // rep0 = ifft(+relu), rep1 = fft
        const float sgn = rep ? -1.0f : 1.0f;

        // ---- Row pass: T[h][v] = sum_w A[h][w] * D^sgn[w][v]
        #pragma unroll
        for (int k = 0; k < 5; ++k)
            #pragma unroll
            for (int j = 0; j < 4; ++j) acc[k][j] = make_float2(0.f, 0.f);

        #pragma unroll
        for (int w = 0; w < NIMG; w += 2) {
            float4 dA0 = *(const float4*)&D[w * NIMG + v0];        // (w, v0..v0+1)
            float4 dB0 = *(const float4*)&D[w * NIMG + v0 + 2];    // (w, v0+2..3)
            float4 dA1 = *(const float4*)&D[(w + 1) * NIMG + v0];
            float4 dB1 = *(const float4*)&D[(w + 1) * NIMG + v0 + 2];
            dA0.y *= sgn; dA0.w *= sgn; dB0.y *= sgn; dB0.w *= sgn;
            dA1.y *= sgn; dA1.w *= sgn; dB1.y *= sgn; dB1.w *= sgn;
            #pragma unroll
            for (int k = 0; k < 5; ++k) {
                const int h = r0 + 8 * k;
                float4 ap = *(const float4*)&Ai[h * NIMG + w];  // A[h][w], A[h][w+1]
                cfma(acc[k][0], ap.x, ap.y, dA0.x, dA0.y);
                cfma(acc[k][0], ap.z, ap.w, dA1.x, dA1.y);
                cfma(acc[k][1], ap.x, ap.y, dA0.z, dA0.w);
                cfma(acc[k][1], ap.z, ap.w, dA1.z, dA1.w);
                cfma(acc[k][2], ap.x, ap.y, dB0.x, dB0.y);
                cfma(acc[k][2], ap.z, ap.w, dB1.x, dB1.y);
                cfma(acc[k][3], ap.x, ap.y, dB0.z, dB0.w);
                cfma(acc[k][3], ap.z, ap.w, dB1.z, dB1.w);
            }
        }
        __syncthreads();
        #pragma unroll
        for (int k = 0; k < 5; ++k) {
            const int h = r0 + 8 * k;
            float4 w0 = make_float4(acc[k][0].x, acc[k][0].y, acc[k][1].x, acc[k][1].y);
            float4 w1 = make_float4(acc[k][2].x, acc[k][2].y, acc[k][3].x, acc[k][3].y);
            *(float4*)&Ai[h * NIMG + v0] = w0;
            *(float4*)&Ai[h * NIMG + v0 + 2] = w1;
        }
        __syncthreads();

        // ---- Col pass: C[u][v] = 0.025 * sum_h D^sgn[u][h] * T[h][v]
        // conj trick: D unconjugated, conj T at load (imag *= sgn), conj result.
        #pragma unroll
        for (int k = 0; k < 5; ++k)
            #pragma unroll
            for (int j = 0; j < 4; ++j) acc[k][j] = make_float2(0.f, 0.f);

        #pragma unroll
        for (int h = 0; h < NIMG; h += 2) {
            float4 t0a = *(const float4*)&Ai[h * NIMG + v0];        // T[h][v0..1]
            float4 t0b = *(const float4*)&Ai[h * NIMG + v0 + 2];
            float4 t1a = *(const float4*)&Ai[(h + 1) * NIMG + v0];
            float4 t1b = *(const float4*)&Ai[(h + 1) * NIMG + v0 + 2];
            t0a.y *= sgn; t0a.w *= sgn; t0b.y *= sgn; t0b.w *= sgn;
            t1a.y *= sgn; t1a.w *= sgn; t1b.y *= sgn; t1b.w *= sgn;
            #pragma unroll
            for (int k = 0; k < 5; ++k) {
                const int u = r0 + 8 * k;
                float4 dp = *(const float4*)&D[u * NIMG + h];  // D[u][h], D[u][h+1]
                cfma(acc[k][0], dp.x, dp.y, t0a.x, t0a.y);
                cfma(acc[k][0], dp.z, dp.w, t1a.x, t1a.y);
                cfma(acc[k][1], dp.x, dp.y, t0a.z, t0a.w);
                cfma(acc[k][1], dp.z, dp.w, t1a.z, t1a.w);
                cfma(acc[k][2], dp.x, dp.y, t0b.x, t0b.y);
                cfma(acc[k][2], dp.z, dp.w, t1b.x, t1b.y);
                cfma(acc[k][3], dp.x, dp.y, t0b.z, t0b.w);
                cfma(acc[k][3], dp.z, dp.w, t1b.z, t1b.w);
            }
        }
        __syncthreads();
        #pragma unroll
        for (int k = 0; k < 5; ++k) {
            const int u = r0 + 8 * k;
            float sx[4], sy[4];
            #pragma unroll
            for (int j = 0; j < 4; ++j) {
                sx[j] = acc[k][j].x * 0.025f;
                sy[j] = acc[k][j].y * 0.025f * sgn;   // undo conj
                if (rep == 0) { sx[j] = fmaxf(sx[j], 0.0f); sy[j] = fmaxf(sy[j], 0.0f); }
            }
            *(float4*)&Ai[u * NIMG + v0]     = make_float4(sx[0], sy[0], sx[1], sy[1]);
            *(float4*)&Ai[u * NIMG + v0 + 2] = make_float4(sx[2], sy[2], sx[3], sy[3]);
        }
        __syncthreads();
    }

    // Coalesced store
    {
        float4* dst = (float4*)(outg + base);
        const float4* src = (const float4*)A;
        #pragma unroll
        for (int k = 0; k < 10; ++k)
            dst[tid + 320 * k] = src[tid + 320 * k];
    }
}

// ---------------------------------------------------------------------------
// Per-frequency channel mix: M[b][o][f] = sum_i F[b][i][f] * W[i][o][f].
// BT=4 batches x OT outputs per thread; W aggregate cache traffic 328 MB.
// ---------------------------------------------------------------------------
template<int INC, int OUTC, int BT, int OT>
__global__ __launch_bounds__(256) void mix_kernel(const float2* __restrict__ F,
                                                  const float2* __restrict__ W,
                                                  float2* __restrict__ M)
{
    const int tid = threadIdx.x;
    const int lane = tid & 63;
    const int wv = tid >> 6;
    const int f = (blockIdx.x % 25) * 64 + lane;
    const int bg = (blockIdx.x / 25) * 4 + wv;
    const int b0 = bg * BT;

    #pragma unroll
    for (int o0 = 0; o0 < OUTC; o0 += OT) {
        float2 acc[BT][OT];
        #pragma unroll
        for (int t = 0; t < BT; ++t)
            #pragma unroll
            for (int o = 0; o < OT; ++o)
                acc[t][o] = make_float2(0.0f, 0.0f);

        for (int i = 0; i < INC; ++i) {
            float2 fv[BT];
            #pragma unroll
            for (int t = 0; t < BT; ++t)
                fv[t] = F[((size_t)(b0 + t) * INC + i) * NPIX + f];
            float2 wr[OT];
            #pragma unroll
            for (int o = 0; o < OT; ++o)
                wr[o] = W[((size_t)i * OUTC + (o0 + o)) * NPIX + f];
            #pragma unroll
            for (int t = 0; t < BT; ++t)
                #pragma unroll
                for (int o = 0; o < OT; ++o)
                    cfma(acc[t][o], fv[t].x, fv[t].y, wr[o].x, wr[o].y);
        }
        #pragma unroll
        for (int t = 0; t < BT; ++t)
            #pragma unroll
            for (int o = 0; o < OT; ++o)
                M[((size_t)(b0 + t) * OUTC + (o0 + o)) * NPIX + f] = acc[t][o];
    }
}

extern "C" void kernel_launch(void* const* d_in, const int* in_sizes, int n_in,
                              void* d_out, int out_size, void* d_ws, size_t ws_size,
                              hipStream_t stream)
{
    const float* x = (const float*)d_in[0];
    const float2* w[6];
    for (int i = 0; i < 6; ++i) w[i] = (const float2*)d_in[1 + i];
    float* out = (float*)d_out;

    const size_t bufBytes = (size_t)256 * 40 * NPIX * sizeof(float2);  // 131 MB
    float2* A = (float2*)d_ws;
    float2* B = (float2*)((char*)d_ws + bufBytes);

    const int FUSEBLK = 256 * 40 / IPB;          // 2560 blocks
    const int MIXBLK = 25 * (256 / 4) / 4;       // 25 fchunks * 16 btiles = 400

    // L1 head: fft(x) (small, 256 images)
    fft2_kernel<true, false, false><<<256, 256, 0, stream>>>(x, A, -1);

    // mix_l -> fused(ifft+relu+fft) for layers 1..5
    mix_kernel<1, 40, 4, 10><<<MIXBLK, 256, 0, stream>>>(A, w[0], B);
    fused_layer_kernel<<<FUSEBLK, 320, 0, stream>>>(B, A);
    for (int l = 1; l <= 4; ++l) {
        mix_kernel<40, 40, 4, 10><<<MIXBLK, 256, 0, stream>>>(A, w[l], B);
        fused_layer_kernel<<<FUSEBLK, 320, 0, stream>>>(B, A);
    }

    // L6: mix(40->1) then final ifft (small, 256 images), real output
    mix_kernel<40, 1, 4, 1><<<MIXBLK, 256, 0, stream>>>(A, w[5], B);
    fft2_kernel<false, false, true><<<256, 256, 0, stream>>>(B, out, +1);
}

// Round 5
// 2822.805 us; speedup vs baseline: 3.0165x; 1.0251x over previous
//
#include <hip/hip_runtime.h>
#include <math.h>

#define NPIX 1600
#define NIMG 40
#define IPB  4          // images per fused block
#define SA   42         // padded LDS row stride (complex): 84 dwords == 20 mod 32
#define SIMG 1682       // padded LDS image stride (complex): 3364 dwords == 4 mod 32

__device__ __forceinline__ void cfma(float2& acc, float ax, float ay, float dx, float dy) {
    // acc += (ax + i*ay) * (dx + i*dy)
    acc.x = fmaf(ax, dx, fmaf(-ay, dy, acc.x));
    acc.y = fmaf(ax, dy, fmaf( ay, dx, acc.y));
}

// ---------------------------------------------------------------------------
// Build global DFT table D[w][v] = e^{+i 2pi (w*v mod 40)/40} (ifft direction;
// forward fft uses conj at the consumer). 12.8 KB, L1/L2-resident.
// ---------------------------------------------------------------------------
__global__ void init_d_kernel(float2* __restrict__ Dg) {
    int idx = blockIdx.x * 256 + threadIdx.x;
    if (idx < NPIX) {
        int w = idx / NIMG, v = idx - (idx / NIMG) * NIMG;
        float ang = 6.28318530717958647692f * (float)((w * v) % NIMG) / 40.0f;
        float s, c;
        sincosf(ang, &s, &c);
        Dg[idx] = make_float2(c, s);
    }
}

// ---------------------------------------------------------------------------
// Small-edge kernel (head/tail only, 256 blocks each) — unchanged.
// ---------------------------------------------------------------------------
template<bool REAL_IN, bool RELU, bool REAL_OUT>
__global__ __launch_bounds__(256) void fft2_kernel(const void* __restrict__ inv,
                                                   void* __restrict__ outv,
                                                   int dir)
{
    const int img = blockIdx.x;
    const int tid = threadIdx.x;
    __shared__ float2 A[NPIX];
    __shared__ float2 T[NPIX];
    __shared__ float2 D[NPIX];
    __shared__ float2 tw[NIMG];

    if (tid < NIMG) {
        float ang = (float)dir * 6.28318530717958647692f * (float)tid / 40.0f;
        float s, c;
        sincosf(ang, &s, &c);
        tw[tid] = make_float2(c, s);
    }
    if (REAL_IN) {
        const float* in = (const float*)inv + (size_t)img * NPIX;
        for (int idx = tid; idx < NPIX; idx += 256)
            A[idx] = make_float2(in[idx], 0.0f);
    } else {
        const float2* in = (const float2*)inv + (size_t)img * NPIX;
        for (int idx = tid; idx < NPIX; idx += 256)
            A[idx] = in[idx];
    }
    __syncthreads();
    for (int idx = tid; idx < NPIX; idx += 256) {
        int a = idx / NIMG, b = idx - a * NIMG;
        D[idx] = tw[(a * b) % NIMG];
    }
    __syncthreads();

    for (int idx = tid; idx < NPIX; idx += 256) {
        int h = idx / NIMG, v = idx - h * NIMG;
        float2 s = make_float2(0.0f, 0.0f);
        const float2* Arow = &A[h * NIMG];
        #pragma unroll
        for (int w = 0; w < NIMG; ++w) {
            float2 a = Arow[w];
            float2 d = D[w * NIMG + v];
            s.x += a.x * d.x - a.y * d.y;
            s.y += a.x * d.y + a.y * d.x;
        }
        T[idx] = s;
    }
    __syncthreads();

    for (int idx = tid; idx < NPIX; idx += 256) {
        int u = idx / NIMG, v = idx - u * NIMG;
        float2 s = make_float2(0.0f, 0.0f);
        const float2* Du = &D[u * NIMG];
        #pragma unroll
        for (int h = 0; h < NIMG; ++h) {
            float2 t = T[h * NIMG + v];
            float2 d = Du[h];
            s.x += t.x * d.x - t.y * d.y;
            s.y += t.x * d.y + t.y * d.x;
        }
        s.x *= 0.025f;
        s.y *= 0.025f;
        if (RELU) { s.x = fmaxf(s.x, 0.0f); s.y = fmaxf(s.y, 0.0f); }
        if (REAL_OUT) {
            ((float*)outv)[(size_t)img * NPIX + idx] = s.x;
        } else {
            ((float2*)outv)[(size_t)img * NPIX + idx] = s;
        }
    }
}

// ---------------------------------------------------------------------------
// Fused ifft2 -> CReLU -> fft2. 320 threads, IPB=4 images. Thread tile:
// v0=4j (j=lo%10) x 5 rows h=r0+8k (r0=lo/10). Conflict control:
//  - LDS rows stride-42 complex (84 dw == 20 mod 32): 8 distinct h -> 8 banks.
//  - image stride 1682 complex (== 4 mod 32): adjacent il rotates bank quads.
//  - lane-varying D reads (row pass) + broadcast D reads (col pass) from the
//    global L1-resident table -> off the LDS pipe entirely.
//  - rep loop unrolled: conj signs + relu + 0.025 fold to compile time.
//  - rep1 col-pass output stores straight to global (skip LDS round-trip).
// LDS 53824 B -> 3 blocks/CU. Model: VALU ~146us floor, LDS ~60, vmem ~45.
// ---------------------------------------------------------------------------
__global__ __launch_bounds__(320) void fused_layer_kernel(const float2* __restrict__ in,
                                                          float2* __restrict__ outg,
                                                          const float4* __restrict__ Dg4)
{
    __shared__ float2 As[IPB * SIMG];   // 53824 B

    const int tid = threadIdx.x;
    const size_t base = (size_t)blockIdx.x * (IPB * NPIX);

    // Coalesced load, stride-42 LDS layout (16B-aligned: v even, 42h even)
    {
        const float4* src = (const float4*)(in + base);
        #pragma unroll
        for (int c = 0; c < 10; ++c) {
            int gidx = tid + 320 * c;          // 0..3199 float4
            int img = gidx / 800;
            int g = gidx - img * 800;          // float4 within image
            int h = g / 20;
            int v = 2 * (g - h * 20);
            float4 val = src[gidx];
            *(float4*)&As[img * SIMG + h * SA + v] = val;
        }
    }
    __syncthreads();

    const int il = tid / 80;
    const int lo = tid - il * 80;
    const int j  = lo % 10;
    const int v0 = 4 * j;
    const int r0 = lo / 10;
    float2* Ai = &As[il * SIMG];

    float2 acc[5][4];

    #pragma unroll
    for (int rep = 0; rep < 2; ++rep) {     // rep0 = ifft(+relu), rep1 = fft
        const float sgn = rep ? -1.0f : 1.0f;

        // ---- Row pass: T[h][v] = sum_w A[h][w] * D^sgn[w][v]
        #pragma unroll
        for (int k = 0; k < 5; ++k)
            #pragma unroll
            for (int q = 0; q < 4; ++q) acc[k][q] = make_float2(0.f, 0.f);

        #pragma unroll 5
        for (int w = 0; w < NIMG; w += 2) {
            float4 d0a = Dg4[w * 20 + 2 * j];          // D[w][v0..v0+1]
            float4 d0b = Dg4[w * 20 + 2 * j + 1];      // D[w][v0+2..v0+3]
            float4 d1a = Dg4[(w + 1) * 20 + 2 * j];
            float4 d1b = Dg4[(w + 1) * 20 + 2 * j + 1];
            d0a.y *= sgn; d0a.w *= sgn; d0b.y *= sgn; d0b.w *= sgn;
            d1a.y *= sgn; d1a.w *= sgn; d1b.y *= sgn; d1b.w *= sgn;
            #pragma unroll
            for (int k = 0; k < 5; ++k) {
                const int h = r0 + 8 * k;
                float4 ap = *(const float4*)&Ai[h * SA + w];  // A[h][w..w+1] (broadcast)
                cfma(acc[k][0], ap.x, ap.y, d0a.x, d0a.y);
                cfma(acc[k][0], ap.z, ap.w, d1a.x, d1a.y);
                cfma(acc[k][1], ap.x, ap.y, d0a.z, d0a.w);
                cfma(acc[k][1], ap.z, ap.w, d1a.z, d1a.w);
                cfma(acc[k][2], ap.x, ap.y, d0b.x, d0b.y);
                cfma(acc[k][2], ap.z, ap.w, d1b.x, d1b.y);
                cfma(acc[k][3], ap.x, ap.y, d0b.z, d0b.w);
                cfma(acc[k][3], ap.z, ap.w, d1b.z, d1b.w);
            }
        }
        __syncthreads();
        #pragma unroll
        for (int k = 0; k < 5; ++k) {
            const int h = r0 + 8 * k;
            *(float4*)&Ai[h * SA + v0]     = make_float4(acc[k][0].x, acc[k][0].y,
                                                         acc[k][1].x, acc[k][1].y);
            *(float4*)&Ai[h * SA + v0 + 2] = make_float4(acc[k][2].x, acc[k][2].y,
                                                         acc[k][3].x, acc[k][3].y);
        }
        __syncthreads();

        // ---- Col pass: C[u][v] = 0.025 * conj^rep( D[u][h] * conj^rep(T[h][v]) )
        #pragma unroll
        for (int k = 0; k < 5; ++k)
            #pragma unroll
            for (int q = 0; q < 4; ++q) acc[k][q] = make_float2(0.f, 0.f);

        #pragma unroll 2
        for (int h = 0; h < NIMG; h += 4) {
            float4 t[4][2];
            #pragma unroll
            for (int r = 0; r < 4; ++r) {
                t[r][0] = *(const float4*)&Ai[(h + r) * SA + v0];      // T[h+r][v0..v0+1]
                t[r][1] = *(const float4*)&Ai[(h + r) * SA + v0 + 2];
                t[r][0].y *= sgn; t[r][0].w *= sgn;
                t[r][1].y *= sgn; t[r][1].w *= sgn;
            }
            #pragma unroll
            for (int k = 0; k < 5; ++k) {
                const int u = r0 + 8 * k;
                float4 da = Dg4[u * 20 + (h >> 1)];        // D[u][h..h+1] (broadcast, L1)
                float4 db = Dg4[u * 20 + (h >> 1) + 1];    // D[u][h+2..h+3]
                cfma(acc[k][0], da.x, da.y, t[0][0].x, t[0][0].y);
                cfma(acc[k][0], da.z, da.w, t[1][0].x, t[1][0].y);
                cfma(acc[k][0], db.x, db.y, t[2][0].x, t[2][0].y);
                cfma(acc[k][0], db.z, db.w, t[3][0].x, t[3][0].y);
                cfma(acc[k][1], da.x, da.y, t[0][0].z, t[0][0].w);
                cfma(acc[k][1], da.z, da.w, t[1][0].z, t[1][0].w);
                cfma(acc[k][1], db.x, db.y, t[2][0].z, t[2][0].w);
                cfma(acc[k][1], db.z, db.w, t[3][0].z, t[3][0].w);
                cfma(acc[k][2], da.x, da.y, t[0][1].x, t[0][1].y);
                cfma(acc[k][2], da.z, da.w, t[1][1].x, t[1][1].y);
                cfma(acc[k][2], db.x, db.y, t[2][1].x, t[2][1].y);
                cfma(acc[k][2], db.z, db.w, t[3][1].x, t[3][1].y);
                cfma(acc[k][3], da.x, da.y, t[0][1].z, t[0][1].w);
                cfma(acc[k][3], da.z, da.w, t[1][1].z, t[1][1].w);
                cfma(acc[k][3], db.x, db.y, t[2][1].z, t[2][1].w);
                cfma(acc[k][3], db.z, db.w, t[3][1].z, t[3][1].w);
            }
        }

        if (rep == 0) {
            // ifft epilogue: scale + CReLU, back into LDS for the fft rep
            __syncthreads();
            #pragma unroll
            for (int k = 0; k < 5; ++k) {
                const int u = r0 + 8 * k;
                float4 o0, o1;
                o0.x = fmaxf(acc[k][0].x * 0.025f, 0.0f);
                o0.y = fmaxf(acc[k][0].y * 0.025f, 0.0f);
                o0.z = fmaxf(acc[k][1].x * 0.025f, 0.0f);
                o0.w = fmaxf(acc[k][1].y * 0.025f, 0.0f);
                o1.x = fmaxf(acc[k][2].x * 0.025f, 0.0f);
                o1.y = fmaxf(acc[k][2].y * 0.025f, 0.0f);
                o1.z = fmaxf(acc[k][3].x * 0.025f, 0.0f);
                o1.w = fmaxf(acc[k][3].y * 0.025f, 0.0f);
                *(float4*)&Ai[u * SA + v0]     = o0;
                *(float4*)&Ai[u * SA + v0 + 2] = o1;
            }
            __syncthreads();
        } else {
            // fft epilogue: scale + undo conj, store straight to global
            float4* out4 = (float4*)(outg + base);
            const int tb = il * 800 + 2 * j;
            #pragma unroll
            for (int k = 0; k < 5; ++k) {
                const int u = r0 + 8 * k;
                float4 o0, o1;
                o0.x =  acc[k][0].x * 0.025f;
                o0.y = -acc[k][0].y * 0.025f;
                o0.z =  acc[k][1].x * 0.025f;
                o0.w = -acc[k][1].y * 0.025f;
                o1.x =  acc[k][2].x * 0.025f;
                o1.y = -acc[k][2].y * 0.025f;
                o1.z =  acc[k][3].x * 0.025f;
                o1.w = -acc[k][3].y * 0.025f;
                out4[tb + u * 20]     = o0;
                out4[tb + u * 20 + 1] = o1;
            }
        }
    }
}

// ---------------------------------------------------------------------------
// Per-frequency channel mix (unchanged): M[b][o][f] = sum_i F[b][i][f]*W[i][o][f]
// ---------------------------------------------------------------------------
template<int INC, int OUTC, int BT, int OT>
__global__ __launch_bounds__(256) void mix_kernel(const float2* __restrict__ F,
                                                  const float2* __restrict__ W,
                                                  float2* __restrict__ M)
{
    const int tid = threadIdx.x;
    const int lane = tid & 63;
    const int wv = tid >> 6;
    const int f = (blockIdx.x % 25) * 64 + lane;
    const int bg = (blockIdx.x / 25) * 4 + wv;
    const int b0 = bg * BT;

    #pragma unroll
    for (int o0 = 0; o0 < OUTC; o0 += OT) {
        float2 acc[BT][OT];
        #pragma unroll
        for (int t = 0; t < BT; ++t)
            #pragma unroll
            for (int o = 0; o < OT; ++o)
                acc[t][o] = make_float2(0.0f, 0.0f);

        for (int i = 0; i < INC; ++i) {
            float2 fv[BT];
            #pragma unroll
            for (int t = 0; t < BT; ++t)
                fv[t] = F[((size_t)(b0 + t) * INC + i) * NPIX + f];
            float2 wr[OT];
            #pragma unroll
            for (int o = 0; o < OT; ++o)
                wr[o] = W[((size_t)i * OUTC + (o0 + o)) * NPIX + f];
            #pragma unroll
            for (int t = 0; t < BT; ++t)
                #pragma unroll
                for (int o = 0; o < OT; ++o)
                    cfma(acc[t][o], fv[t].x, fv[t].y, wr[o].x, wr[o].y);
        }
        #pragma unroll
        for (int t = 0; t < BT; ++t)
            #pragma unroll
            for (int o = 0; o < OT; ++o)
                M[((size_t)(b0 + t) * OUTC + (o0 + o)) * NPIX + f] = acc[t][o];
    }
}

extern "C" void kernel_launch(void* const* d_in, const int* in_sizes, int n_in,
                              void* d_out, int out_size, void* d_ws, size_t ws_size,
                              hipStream_t stream)
{
    const float* x = (const float*)d_in[0];
    const float2* w[6];
    for (int i = 0; i < 6; ++i) w[i] = (const float2*)d_in[1 + i];
    float* out = (float*)d_out;

    const size_t bufBytes = (size_t)256 * 40 * NPIX * sizeof(float2);  // 131.072 MB
    float2* A  = (float2*)d_ws;
    float2* B  = (float2*)((char*)d_ws + bufBytes);
    float2* Dg = (float2*)((char*)d_ws + 2 * bufBytes);                // 12.8 KB table

    const int FUSEBLK = 256 * 40 / IPB;          // 2560 blocks
    const int MIXBLK = 25 * (256 / 4) / 4;       // 400

    init_d_kernel<<<7, 256, 0, stream>>>(Dg);

    // L1 head: fft(x) (small, 256 images)
    fft2_kernel<true, false, false><<<256, 256, 0, stream>>>(x, A, -1);

    // mix_l -> fused(ifft+relu+fft) for layers 1..5
    mix_kernel<1, 40, 4, 10><<<MIXBLK, 256, 0, stream>>>(A, w[0], B);
    fused_layer_kernel<<<FUSEBLK, 320, 0, stream>>>(B, A, (const float4*)Dg);
    for (int l = 1; l <= 4; ++l) {
        mix_kernel<40, 40, 4, 10><<<MIXBLK, 256, 0, stream>>>(A, w[l], B);
        fused_layer_kernel<<<FUSEBLK, 320, 0, stream>>>(B, A, (const float4*)Dg);
    }

    // L6: mix(40->1) then final ifft (small, 256 images), real output
    mix_kernel<40, 1, 4, 1><<<MIXBLK, 256, 0, stream>>>(A, w[5], B);
    fft2_kernel<false, false, true><<<256, 256, 0, stream>>>(B, out, +1);
}

// Round 6
// 2437.533 us; speedup vs baseline: 3.4933x; 1.1581x over previous
//
#include <hip/hip_runtime.h>
#include <math.h>

#define NPIX 1600
#define NIMG 40
#define SA   41   // padded LDS row stride (complex): 82 dwords == 18 mod 32

__device__ __forceinline__ void cfma(float2& acc, float ax, float ay, float bx, float by) {
    // acc += (ax + i*ay) * (bx + i*by)
    acc.x = fmaf(ax, bx, fmaf(-ay, by, acc.x));
    acc.y = fmaf(ax, by, fmaf( ay, bx, acc.y));
}

// ---------------------------------------------------------------------------
// Operand tables for the fused kernel, conj baked in (no sign-mults at use):
//   Drow*[w][j][slot<5]  = D^dir[w][5j+slot]      (row pass, lane-varying in j)
//   Dcol*[h][r0][slot<5] = D^dir[r0+8*slot][h]    (col pass, broadcast per r0)
// slot==5 is zero padding so each (w,j) record is 48 B = 3 float4 loads.
// 4 tables x 15360 B = 61 KB, L1/L2-resident.
// ---------------------------------------------------------------------------
__global__ void init_tables(float2* __restrict__ DrI, float2* __restrict__ DrF,
                            float2* __restrict__ DcI, float2* __restrict__ DcF)
{
    int idx = blockIdx.x * 256 + threadIdx.x;
    if (idx >= NIMG * 8 * 6) return;
    int wh   = idx / 48;
    int rem  = idx - wh * 48;
    int pj   = rem / 6;
    int slot = rem - pj * 6;
    float2 zr = make_float2(0.f, 0.f);
    float2 rI = zr, rF = zr, cI = zr, cF = zr;
    if (slot < 5) {
        int v = 5 * pj + slot;
        float s1, c1;
        sincosf(6.28318530717958647692f * (float)((wh * v) % NIMG) / 40.0f, &s1, &c1);
        rI = make_float2(c1,  s1);   // ifft direction e^{+i}
        rF = make_float2(c1, -s1);   // forward fft e^{-i}
        int u = pj + 8 * slot;
        float s2, c2;
        sincosf(6.28318530717958647692f * (float)((u * wh) % NIMG) / 40.0f, &s2, &c2);
        cI = make_float2(c2,  s2);
        cF = make_float2(c2, -s2);
    }
    DrI[idx] = rI; DrF[idx] = rF; DcI[idx] = cI; DcF[idx] = cF;
}

// ---------------------------------------------------------------------------
// Small-edge kernel (head/tail only, 256 blocks each) — unchanged.
// ---------------------------------------------------------------------------
template<bool REAL_IN, bool RELU, bool REAL_OUT>
__global__ __launch_bounds__(256) void fft2_kernel(const void* __restrict__ inv,
                                                   void* __restrict__ outv,
                                                   int dir)
{
    const int img = blockIdx.x;
    const int tid = threadIdx.x;
    __shared__ float2 A[NPIX];
    __shared__ float2 T[NPIX];
    __shared__ float2 D[NPIX];
    __shared__ float2 tw[NIMG];

    if (tid < NIMG) {
        float ang = (float)dir * 6.28318530717958647692f * (float)tid / 40.0f;
        float s, c;
        sincosf(ang, &s, &c);
        tw[tid] = make_float2(c, s);
    }
    if (REAL_IN) {
        const float* in = (const float*)inv + (size_t)img * NPIX;
        for (int idx = tid; idx < NPIX; idx += 256)
            A[idx] = make_float2(in[idx], 0.0f);
    } else {
        const float2* in = (const float2*)inv + (size_t)img * NPIX;
        for (int idx = tid; idx < NPIX; idx += 256)
            A[idx] = in[idx];
    }
    __syncthreads();
    for (int idx = tid; idx < NPIX; idx += 256) {
        int a = idx / NIMG, b = idx - a * NIMG;
        D[idx] = tw[(a * b) % NIMG];
    }
    __syncthreads();

    for (int idx = tid; idx < NPIX; idx += 256) {
        int h = idx / NIMG, v = idx - h * NIMG;
        float2 s = make_float2(0.0f, 0.0f);
        const float2* Arow = &A[h * NIMG];
        #pragma unroll
        for (int w = 0; w < NIMG; ++w) {
            float2 a = Arow[w];
            float2 d = D[w * NIMG + v];
            s.x += a.x * d.x - a.y * d.y;
            s.y += a.x * d.y + a.y * d.x;
        }
        T[idx] = s;
    }
    __syncthreads();

    for (int idx = tid; idx < NPIX; idx += 256) {
        int u = idx / NIMG, v = idx - u * NIMG;
        float2 s = make_float2(0.0f, 0.0f);
        const float2* Du = &D[u * NIMG];
        #pragma unroll
        for (int h = 0; h < NIMG; ++h) {
            float2 t = T[h * NIMG + v];
            float2 d = Du[h];
            s.x += t.x * d.x - t.y * d.y;
            s.y += t.x * d.y + t.y * d.x;
        }
        s.x *= 0.025f;
        s.y *= 0.025f;
        if (RELU) { s.x = fmaxf(s.x, 0.0f); s.y = fmaxf(s.y, 0.0f); }
        if (REAL_OUT) {
            ((float*)outv)[(size_t)img * NPIX + idx] = s.x;
        } else {
            ((float2*)outv)[(size_t)img * NPIX + idx] = s;
        }
    }
}

// ---------------------------------------------------------------------------
// Row pass: T[h][v] = sum_w A[h][w] * Drow[w][v-group], thread tile 5h x 5v,
// h = r0+8k, v = 5j+c. A read as b128 (w-pairs; rows 16B-aligned). Banks:
// 8 distinct rows * stride-18 banks -> conflict-free.
// ---------------------------------------------------------------------------
__device__ __forceinline__ void pass_row(const float2* __restrict__ As,
                                         const float4* __restrict__ Dr,
                                         int j, int r0, float2 (&acc)[5][5])
{
    #pragma unroll
    for (int k = 0; k < 5; ++k)
        #pragma unroll
        for (int c = 0; c < 5; ++c) acc[k][c] = make_float2(0.f, 0.f);

    #pragma unroll 2
    for (int w = 0; w < NIMG; w += 2) {
        const float4* dp0 = &Dr[(w * 8 + j) * 3];
        const float4* dp1 = &Dr[((w + 1) * 8 + j) * 3];
        float4 e0 = dp0[0], e1 = dp0[1], e2 = dp0[2];
        float4 g0 = dp1[0], g1 = dp1[1], g2 = dp1[2];
        float4 ap[5];
        #pragma unroll
        for (int k = 0; k < 5; ++k)
            ap[k] = *(const float4*)&As[(r0 + 8 * k) * SA + w];  // A[h][w], A[h][w+1]
        #pragma unroll
        for (int k = 0; k < 5; ++k) {
            cfma(acc[k][0], ap[k].x, ap[k].y, e0.x, e0.y);
            cfma(acc[k][1], ap[k].x, ap[k].y, e0.z, e0.w);
            cfma(acc[k][2], ap[k].x, ap[k].y, e1.x, e1.y);
            cfma(acc[k][3], ap[k].x, ap[k].y, e1.z, e1.w);
            cfma(acc[k][4], ap[k].x, ap[k].y, e2.x, e2.y);
            cfma(acc[k][0], ap[k].z, ap[k].w, g0.x, g0.y);
            cfma(acc[k][1], ap[k].z, ap[k].w, g0.z, g0.w);
            cfma(acc[k][2], ap[k].z, ap[k].w, g1.x, g1.y);
            cfma(acc[k][3], ap[k].z, ap[k].w, g1.z, g1.w);
            cfma(acc[k][4], ap[k].z, ap[k].w, g2.x, g2.y);
        }
    }
}

// ---------------------------------------------------------------------------
// Col pass: C[u][v] = sum_h Dcol[u][h] * T[h][v]. T reads: uniform row h,
// 8 distinct j-offsets (banks 10j+2c: distinct) -> conflict-free b64.
// ---------------------------------------------------------------------------
__device__ __forceinline__ void pass_col(const float2* __restrict__ As,
                                         const float4* __restrict__ Dc,
                                         int j, int r0, float2 (&acc)[5][5])
{
    #pragma unroll
    for (int k = 0; k < 5; ++k)
        #pragma unroll
        for (int c = 0; c < 5; ++c) acc[k][c] = make_float2(0.f, 0.f);

    #pragma unroll 2
    for (int h = 0; h < NIMG; ++h) {
        const float4* dp = &Dc[(h * 8 + r0) * 3];
        float4 f0 = dp[0], f1 = dp[1], f2 = dp[2];
        float2 t[5];
        #pragma unroll
        for (int c = 0; c < 5; ++c)
            t[c] = As[h * SA + 5 * j + c];
        #pragma unroll
        for (int c = 0; c < 5; ++c) {
            cfma(acc[0][c], f0.x, f0.y, t[c].x, t[c].y);
            cfma(acc[1][c], f0.z, f0.w, t[c].x, t[c].y);
            cfma(acc[2][c], f1.x, f1.y, t[c].x, t[c].y);
            cfma(acc[3][c], f1.z, f1.w, t[c].x, t[c].y);
            cfma(acc[4][c], f2.x, f2.y, t[c].x, t[c].y);
        }
    }
}

// ---------------------------------------------------------------------------
// Fused ifft2 -> CReLU -> fft2. ONE WAVE PER IMAGE: 64 threads, LDS = one
// padded image (13120 B) -> 12 blocks/CU, every barrier is single-wave
// (near-free, no cross-wave drain coupling). Thread tile 5x5; conj baked
// into the fwd tables so zero sign-mults. VALU-bound by design:
// per wave ~17k VALU instr vs ~5.2k LDS cyc vs ~500 vmem (L1 tables).
// ---------------------------------------------------------------------------
__global__ __launch_bounds__(64, 2) void fused_layer_kernel(
    const float2* __restrict__ in, float2* __restrict__ outg,
    const float4* __restrict__ DrI, const float4* __restrict__ DrF,
    const float4* __restrict__ DcI, const float4* __restrict__ DcF)
{
    __shared__ float2 As[NIMG * SA];   // 13120 B

    const int lane = threadIdx.x;
    const int j  = lane >> 3;          // v-group: v = 5j + c
    const int r0 = lane & 7;           // row-group: h = r0 + 8k
    const size_t base = (size_t)blockIdx.x * NPIX;

    // Stage image (coalesced b64, 25 per thread)
    {
        const float2* src = in + base;
        #pragma unroll
        for (int c = 0; c < 25; ++c) {
            int gidx = c * 64 + lane;
            int h = gidx / NIMG;
            int v = gidx - h * NIMG;
            As[h * SA + v] = src[gidx];
        }
    }
    __syncthreads();

    float2 acc[5][5];

    // ---- rep0: ifft2 + CReLU ----
    pass_row(As, DrI, j, r0, acc);
    __syncthreads();
    #pragma unroll
    for (int k = 0; k < 5; ++k)
        #pragma unroll
        for (int c = 0; c < 5; ++c)
            As[(r0 + 8 * k) * SA + 5 * j + c] = acc[k][c];
    __syncthreads();
    pass_col(As, DcI, j, r0, acc);
    __syncthreads();
    #pragma unroll
    for (int k = 0; k < 5; ++k)
        #pragma unroll
        for (int c = 0; c < 5; ++c)
            As[(r0 + 8 * k) * SA + 5 * j + c] =
                make_float2(fmaxf(acc[k][c].x * 0.025f, 0.f),
                            fmaxf(acc[k][c].y * 0.025f, 0.f));
    __syncthreads();

    // ---- rep1: forward fft2, direct global store ----
    pass_row(As, DrF, j, r0, acc);
    __syncthreads();
    #pragma unroll
    for (int k = 0; k < 5; ++k)
        #pragma unroll
        for (int c = 0; c < 5; ++c)
            As[(r0 + 8 * k) * SA + 5 * j + c] = acc[k][c];
    __syncthreads();
    pass_col(As, DcF, j, r0, acc);

    {
        float2* dst = outg + base;
        #pragma unroll
        for (int k = 0; k < 5; ++k)
            #pragma unroll
            for (int c = 0; c < 5; ++c)
                dst[(r0 + 8 * k) * NIMG + 5 * j + c] =
                    make_float2(acc[k][c].x * 0.025f, acc[k][c].y * 0.025f);
    }
}

// ---------------------------------------------------------------------------
// Per-frequency channel mix (unchanged): M[b][o][f] = sum_i F[b][i][f]*W[i][o][f]
// ---------------------------------------------------------------------------
template<int INC, int OUTC, int BT, int OT>
__global__ __launch_bounds__(256) void mix_kernel(const float2* __restrict__ F,
                                                  const float2* __restrict__ W,
                                                  float2* __restrict__ M)
{
    const int tid = threadIdx.x;
    const int lane = tid & 63;
    const int wv = tid >> 6;
    const int f = (blockIdx.x % 25) * 64 + lane;
    const int bg = (blockIdx.x / 25) * 4 + wv;
    const int b0 = bg * BT;

    #pragma unroll
    for (int o0 = 0; o0 < OUTC; o0 += OT) {
        float2 acc[BT][OT];
        #pragma unroll
        for (int t = 0; t < BT; ++t)
            #pragma unroll
            for (int o = 0; o < OT; ++o)
                acc[t][o] = make_float2(0.0f, 0.0f);

        for (int i = 0; i < INC; ++i) {
            float2 fv[BT];
            #pragma unroll
            for (int t = 0; t < BT; ++t)
                fv[t] = F[((size_t)(b0 + t) * INC + i) * NPIX + f];
            float2 wr[OT];
            #pragma unroll
            for (int o = 0; o < OT; ++o)
                wr[o] = W[((size_t)i * OUTC + (o0 + o)) * NPIX + f];
            #pragma unroll
            for (int t = 0; t < BT; ++t)
                #pragma unroll
                for (int o = 0; o < OT; ++o)
                    cfma(acc[t][o], fv[t].x, fv[t].y, wr[o].x, wr[o].y);
        }
        #pragma unroll
        for (int t = 0; t < BT; ++t)
            #pragma unroll
            for (int o = 0; o < OT; ++o)
                M[((size_t)(b0 + t) * OUTC + (o0 + o)) * NPIX + f] = acc[t][o];
    }
}

extern "C" void kernel_launch(void* const* d_in, const int* in_sizes, int n_in,
                              void* d_out, int out_size, void* d_ws, size_t ws_size,
                              hipStream_t stream)
{
    const float* x = (const float*)d_in[0];
    const float2* w[6];
    for (int i = 0; i < 6; ++i) w[i] = (const float2*)d_in[1 + i];
    float* out = (float*)d_out;

    const size_t bufBytes = (size_t)256 * 40 * NPIX * sizeof(float2);  // 131.072 MB
    const size_t tabBytes = (size_t)NIMG * 8 * 6 * sizeof(float2);     // 15360 B
    float2* A   = (float2*)d_ws;
    float2* B   = (float2*)((char*)d_ws + bufBytes);
    char*   tb  = (char*)d_ws + 2 * bufBytes;
    float2* DrI = (float2*)(tb);
    float2* DrF = (float2*)(tb + tabBytes);
    float2* DcI = (float2*)(tb + 2 * tabBytes);
    float2* DcF = (float2*)(tb + 3 * tabBytes);

    const int FUSEBLK = 256 * 40;              // one block (wave) per image
    const int MIXBLK = 25 * (256 / 4) / 4;     // 400

    init_tables<<<8, 256, 0, stream>>>(DrI, DrF, DcI, DcF);

    // L1 head: fft(x) (small, 256 images)
    fft2_kernel<true, false, false><<<256, 256, 0, stream>>>(x, A, -1);

    // mix_l -> fused(ifft+relu+fft) for layers 1..5
    mix_kernel<1, 40, 4, 10><<<MIXBLK, 256, 0, stream>>>(A, w[0], B);
    fused_layer_kernel<<<FUSEBLK, 64, 0, stream>>>(B, A,
        (const float4*)DrI, (const float4*)DrF, (const float4*)DcI, (const float4*)DcF);
    for (int l = 1; l <= 4; ++l) {
        mix_kernel<40, 40, 4, 10><<<MIXBLK, 256, 0, stream>>>(A, w[l], B);
        fused_layer_kernel<<<FUSEBLK, 64, 0, stream>>>(B, A,
            (const float4*)DrI, (const float4*)DrF, (const float4*)DcI, (const float4*)DcF);
    }

    // L6: mix(40->1) then final ifft (small, 256 images), real output
    mix_kernel<40, 1, 4, 1><<<MIXBLK, 256, 0, stream>>>(A, w[5], B);
    fft2_kernel<false, false, true><<<256, 256, 0, stream>>>(B, out, +1);
}

// Round 7
// 1949.177 us; speedup vs baseline: 4.3685x; 1.2505x over previous
//
#include <hip/hip_runtime.h>
#include <math.h>

#define NPIX 1600
#define NIMG 40
#define ST   50    // A-buf row stride (complex), 16B-aligned
#define SH   48    // T-plane row stride (bf16)

typedef __bf16 bf16x8 __attribute__((ext_vector_type(8)));
typedef float  f32x4  __attribute__((ext_vector_type(4)));
#define MFMA __builtin_amdgcn_mfma_f32_16x16x32_bf16

__device__ __forceinline__ void cfma(float2& acc, float ax, float ay, float bx, float by) {
    acc.x = fmaf(ax, bx, fmaf(-ay, by, acc.x));
    acc.y = fmaf(ax, by, fmaf( ay, bx, acc.y));
}

// ---------------------------------------------------------------------------
// D table in MFMA B-fragment order. Record (kc,t,p): 64 lanes x 8 bf16 (16B):
//   lane holds D[k = kc*32 + (lane>>4)*8 + j][n = t*16 + (lane&15)], j=0..7
// planes p: 0=Dr_hi 1=Dr_lo 2=Di_hi 3=Di_lo 4=(-Di)_hi 5=(-Di)_lo  (ifft dir)
// Forward fft = conj: swap roles of planes {2,3} and {4,5} at use site.
// D symmetric => same record serves A-operand fragments (col pass).
// Zero outside k<40, n<40.
// ---------------------------------------------------------------------------
__global__ void init_dtab(unsigned short* __restrict__ Dtab) {
    int idx = blockIdx.x * 256 + threadIdx.x;   // 36 recs * 64 lanes = 2304
    if (idx >= 2304) return;
    int rec = idx >> 6, lane = idx & 63;
    int p = rec % 6, t = (rec / 6) % 3, kc = rec / 18;
    unsigned short out[8];
    for (int j = 0; j < 8; ++j) {
        int k = kc * 32 + (lane >> 4) * 8 + j;
        int n = t * 16 + (lane & 15);
        float val = 0.0f;
        if (k < 40 && n < 40) {
            float ang = 6.28318530717958647692f * (float)((k * n) % 40) / 40.0f;
            float dr, di, s, c;
            sincosf(ang, &s, &c);
            dr = c; di = s;
            float base = (p < 2) ? dr : (p < 4) ? di : -di;
            __bf16 hi = (__bf16)base;
            if ((p & 1) == 0) val = (float)hi;
            else              val = (float)(__bf16)(base - (float)hi);
        }
        out[j] = __builtin_bit_cast(unsigned short, (__bf16)val);
    }
    unsigned short* dst = Dtab + (size_t)rec * 512 + lane * 8;
    for (int j = 0; j < 8; ++j) dst[j] = out[j];
}

// ---------------------------------------------------------------------------
// Small-edge fp32 kernel (head/tail only, 256 blocks each) — unchanged.
// ---------------------------------------------------------------------------
template<bool REAL_IN, bool RELU, bool REAL_OUT>
__global__ __launch_bounds__(256) void fft2_kernel(const void* __restrict__ inv,
                                                   void* __restrict__ outv,
                                                   int dir)
{
    const int img = blockIdx.x;
    const int tid = threadIdx.x;
    __shared__ float2 A[NPIX];
    __shared__ float2 T[NPIX];
    __shared__ float2 D[NPIX];
    __shared__ float2 tw[NIMG];

    if (tid < NIMG) {
        float ang = (float)dir * 6.28318530717958647692f * (float)tid / 40.0f;
        float s, c;
        sincosf(ang, &s, &c);
        tw[tid] = make_float2(c, s);
    }
    if (REAL_IN) {
        const float* in = (const float*)inv + (size_t)img * NPIX;
        for (int idx = tid; idx < NPIX; idx += 256)
            A[idx] = make_float2(in[idx], 0.0f);
    } else {
        const float2* in = (const float2*)inv + (size_t)img * NPIX;
        for (int idx = tid; idx < NPIX; idx += 256)
            A[idx] = in[idx];
    }
    __syncthreads();
    for (int idx = tid; idx < NPIX; idx += 256) {
        int a = idx / NIMG, b = idx - a * NIMG;
        D[idx] = tw[(a * b) % NIMG];
    }
    __syncthreads();

    for (int idx = tid; idx < NPIX; idx += 256) {
        int h = idx / NIMG, v = idx - h * NIMG;
        float2 s = make_float2(0.0f, 0.0f);
        const float2* Arow = &A[h * NIMG];
        #pragma unroll
        for (int w = 0; w < NIMG; ++w) {
            float2 a = Arow[w];
            float2 d = D[w * NIMG + v];
            s.x += a.x * d.x - a.y * d.y;
            s.y += a.x * d.y + a.y * d.x;
        }
        T[idx] = s;
    }
    __syncthreads();

    for (int idx = tid; idx < NPIX; idx += 256) {
        int u = idx / NIMG, v = idx - u * NIMG;
        float2 s = make_float2(0.0f, 0.0f);
        const float2* Du = &D[u * NIMG];
        #pragma unroll
        for (int h = 0; h < NIMG; ++h) {
            float2 t = T[h * NIMG + v];
            float2 d = Du[h];
            s.x += t.x * d.x - t.y * d.y;
            s.y += t.x * d.y + t.y * d.x;
        }
        s.x *= 0.025f;
        s.y *= 0.025f;
        if (RELU) { s.x = fmaxf(s.x, 0.0f); s.y = fmaxf(s.y, 0.0f); }
        if (REAL_OUT) {
            ((float*)outv)[(size_t)img * NPIX + idx] = s.x;
        } else {
            ((float2*)outv)[(size_t)img * NPIX + idx] = s;
        }
    }
}

// 12-mfma complex tile update, negation carried by the D "n" planes.
// Row pass: A-operand = activation planes (x*), B-operand = D planes.
__device__ __forceinline__ void mac_row(f32x4& aR, f32x4& aI,
    bf16x8 xrh, bf16x8 xrl, bf16x8 xih, bf16x8 xil,
    bf16x8 drh, bf16x8 drl, bf16x8 dih, bf16x8 dil, bf16x8 dnh, bf16x8 dnl)
{
    aR = MFMA(xrh, drh, aR, 0, 0, 0);
    aR = MFMA(xrl, drh, aR, 0, 0, 0);
    aR = MFMA(xrh, drl, aR, 0, 0, 0);
    aR = MFMA(xih, dnh, aR, 0, 0, 0);
    aR = MFMA(xil, dnh, aR, 0, 0, 0);
    aR = MFMA(xih, dnl, aR, 0, 0, 0);
    aI = MFMA(xrh, dih, aI, 0, 0, 0);
    aI = MFMA(xrl, dih, aI, 0, 0, 0);
    aI = MFMA(xrh, dil, aI, 0, 0, 0);
    aI = MFMA(xih, drh, aI, 0, 0, 0);
    aI = MFMA(xil, drh, aI, 0, 0, 0);
    aI = MFMA(xih, drl, aI, 0, 0, 0);
}

// Col pass: A-operand = D planes, B-operand = T planes (t*).
__device__ __forceinline__ void mac_col(f32x4& aR, f32x4& aI,
    bf16x8 drh, bf16x8 drl, bf16x8 dih, bf16x8 dil, bf16x8 dnh, bf16x8 dnl,
    bf16x8 trh, bf16x8 trl, bf16x8 tih, bf16x8 til)
{
    aR = MFMA(drh, trh, aR, 0, 0, 0);
    aR = MFMA(drl, trh, aR, 0, 0, 0);
    aR = MFMA(drh, trl, aR, 0, 0, 0);
    aR = MFMA(dnh, tih, aR, 0, 0, 0);
    aR = MFMA(dnl, tih, aR, 0, 0, 0);
    aR = MFMA(dnh, til, aR, 0, 0, 0);
    aI = MFMA(drh, tih, aI, 0, 0, 0);
    aI = MFMA(drl, tih, aI, 0, 0, 0);
    aI = MFMA(drh, til, aI, 0, 0, 0);
    aI = MFMA(dih, trh, aI, 0, 0, 0);
    aI = MFMA(dil, trh, aI, 0, 0, 0);
    aI = MFMA(dih, trl, aI, 0, 0, 0);
}

// ---------------------------------------------------------------------------
// Fused ifft2 -> CReLU -> fft2 on MFMA. One wave per image. Per rep:
//   row pass: T = A · D   (A from LDS fp32, D from global frag table)
//   col pass: C = D · T   (T from LDS split-bf16 planes, D from table)
// A-buf (48x50 float2, 19200 B) overlaid by 4 T-planes (48x48 bf16, 18432 B).
// 19.2 KB LDS -> 8 blocks/CU. Split-bf16: X ~ Xh+Xl, drop lo*lo (~2^-18 rel).
// ---------------------------------------------------------------------------
__global__ __launch_bounds__(64) void fused_mfma_kernel(const float2* __restrict__ in,
                                                        float2* __restrict__ outg,
                                                        const unsigned short* __restrict__ Dtab)
{
    __shared__ alignas(16) char smem[19200];
    float2* As = (float2*)smem;
    unsigned short* Tp = (unsigned short*)smem;   // 4 planes of 48*48 bf16

    const int lane = threadIdx.x;
    const int q = lane >> 4;
    const int m = lane & 15;
    const size_t base = (size_t)blockIdx.x * NPIX;

    // ---- Stage image (800 float4) + zero pad rows 40..47
    {
        const float4* src = (const float4*)(in + base);
        #pragma unroll
        for (int c = 0; c < 13; ++c) {
            int p = c * 64 + lane;
            if (p < 800) {
                float4 val = src[p];
                int h = p / 20, w2 = (p - h * 20) * 2;
                *(float4*)&As[h * ST + w2] = val;
            }
        }
        #pragma unroll
        for (int c = 0; c < 3; ++c) {
            int idx = c * 64 + lane;                  // 192 float4 = rows 40..47 x cols 0..47
            int r = 40 + idx / 24, w2 = (idx - (idx / 24) * 24) * 2;
            *(float4*)&As[r * ST + w2] = make_float4(0.f, 0.f, 0.f, 0.f);
        }
    }
    __syncthreads();

    f32x4 accR[3][3], accI[3][3];

    #pragma unroll
    for (int rep = 0; rep < 2; ++rep) {
        const int IP = rep ? 4 : 2;   // +i-plane pair base (fwd uses -sin)
        const int IN = rep ? 2 : 4;   // -i-plane pair base

        // ================= Row pass: T = A * D =================
        #pragma unroll
        for (int a = 0; a < 3; ++a)
            #pragma unroll
            for (int b = 0; b < 3; ++b) {
                accR[a][b] = (f32x4){0.f, 0.f, 0.f, 0.f};
                accI[a][b] = (f32x4){0.f, 0.f, 0.f, 0.f};
            }

        #pragma unroll
        for (int kc = 0; kc < 2; ++kc) {
            bf16x8 arh[3], arl[3], aih[3], ail[3];
            const bool have = (kc == 0) || (q == 0);
            #pragma unroll
            for (int mt = 0; mt < 3; ++mt) {
                float re[8], im[8];
                if (have) {
                    int row = mt * 16 + m, wb = kc * 32 + q * 8;
                    #pragma unroll
                    for (int t4 = 0; t4 < 4; ++t4) {
                        float4 v = *(const float4*)&As[row * ST + wb + t4 * 2];
                        re[2 * t4]     = v.x; im[2 * t4]     = v.y;
                        re[2 * t4 + 1] = v.z; im[2 * t4 + 1] = v.w;
                    }
                } else {
                    #pragma unroll
                    for (int j = 0; j < 8; ++j) { re[j] = 0.f; im[j] = 0.f; }
                }
                #pragma unroll
                for (int j = 0; j < 8; ++j) {
                    __bf16 h1 = (__bf16)re[j];
                    arh[mt][j] = h1;
                    arl[mt][j] = (__bf16)(re[j] - (float)h1);
                    __bf16 h2 = (__bf16)im[j];
                    aih[mt][j] = h2;
                    ail[mt][j] = (__bf16)(im[j] - (float)h2);
                }
            }
            #pragma unroll
            for (int nt = 0; nt < 3; ++nt) {
                const bf16x8* rec = (const bf16x8*)(Dtab + ((size_t)(kc * 3 + nt) * 6) * 512) + lane;
                bf16x8 drh = rec[0 * 64], drl = rec[1 * 64];
                bf16x8 dih = rec[IP * 64], dil = rec[(IP + 1) * 64];
                bf16x8 dnh = rec[IN * 64], dnl = rec[(IN + 1) * 64];
                #pragma unroll
                for (int mt = 0; mt < 3; ++mt)
                    mac_row(accR[mt][nt], accI[mt][nt],
                            arh[mt], arl[mt], aih[mt], ail[mt],
                            drh, drl, dih, dil, dnh, dnl);
            }
        }
        __syncthreads();

        // ---- T epilogue: split to 4 bf16 planes [v][h] (h<40 rows only)
        #pragma unroll
        for (int mt = 0; mt < 3; ++mt) {
            int hb = mt * 16 + q * 4;
            if (hb < 40) {
                #pragma unroll
                for (int nt = 0; nt < 3; ++nt) {
                    int v = nt * 16 + m;
                    f32x4 r = accR[mt][nt], i = accI[mt][nt];
                    ushort4 srh, srl, sih, sil;
                    unsigned short* prh = (unsigned short*)&srh;
                    unsigned short* prl = (unsigned short*)&srl;
                    unsigned short* pih = (unsigned short*)&sih;
                    unsigned short* pil = (unsigned short*)&sil;
                    #pragma unroll
                    for (int g = 0; g < 4; ++g) {
                        __bf16 h1 = (__bf16)r[g];
                        prh[g] = __builtin_bit_cast(unsigned short, h1);
                        prl[g] = __builtin_bit_cast(unsigned short, (__bf16)(r[g] - (float)h1));
                        __bf16 h2 = (__bf16)i[g];
                        pih[g] = __builtin_bit_cast(unsigned short, h2);
                        pil[g] = __builtin_bit_cast(unsigned short, (__bf16)(i[g] - (float)h2));
                    }
                    *(ushort4*)&Tp[0 * 2304 + v * SH + hb] = srh;
                    *(ushort4*)&Tp[1 * 2304 + v * SH + hb] = srl;
                    *(ushort4*)&Tp[2 * 2304 + v * SH + hb] = sih;
                    *(ushort4*)&Tp[3 * 2304 + v * SH + hb] = sil;
                }
            }
        }
        __syncthreads();

        // ================= Col pass: C = D * T =================
        #pragma unroll
        for (int a = 0; a < 3; ++a)
            #pragma unroll
            for (int b = 0; b < 3; ++b) {
                accR[a][b] = (f32x4){0.f, 0.f, 0.f, 0.f};
                accI[a][b] = (f32x4){0.f, 0.f, 0.f, 0.f};
            }

        #pragma unroll
        for (int kc = 0; kc < 2; ++kc) {
            bf16x8 trh[3], trl[3], tih[3], til[3];
            const bool have = (kc == 0) || (q == 0);
            #pragma unroll
            for (int nt = 0; nt < 3; ++nt) {
                trh[nt] = (bf16x8){}; trl[nt] = (bf16x8){};
                tih[nt] = (bf16x8){}; til[nt] = (bf16x8){};
                if (have) {
                    int v = nt * 16 + m, hb = kc * 32 + q * 8;
                    trh[nt] = *(const bf16x8*)&Tp[0 * 2304 + v * SH + hb];
                    trl[nt] = *(const bf16x8*)&Tp[1 * 2304 + v * SH + hb];
                    tih[nt] = *(const bf16x8*)&Tp[2 * 2304 + v * SH + hb];
                    til[nt] = *(const bf16x8*)&Tp[3 * 2304 + v * SH + hb];
                }
            }
            #pragma unroll
            for (int mt = 0; mt < 3; ++mt) {
                const bf16x8* rec = (const bf16x8*)(Dtab + ((size_t)(kc * 3 + mt) * 6) * 512) + lane;
                bf16x8 drh = rec[0 * 64], drl = rec[1 * 64];
                bf16x8 dih = rec[IP * 64], dil = rec[(IP + 1) * 64];
                bf16x8 dnh = rec[IN * 64], dnl = rec[(IN + 1) * 64];
                #pragma unroll
                for (int nt = 0; nt < 3; ++nt)
                    mac_col(accR[mt][nt], accI[mt][nt],
                            drh, drl, dih, dil, dnh, dnl,
                            trh[nt], trl[nt], tih[nt], til[nt]);
            }
        }
        __syncthreads();

        // ---- Col epilogue
        if (rep == 0) {
            // scale + CReLU, rebuild A-buf (fp32) for rep1
            #pragma unroll
            for (int mt = 0; mt < 3; ++mt) {
                int u0 = mt * 16 + q * 4;
                if (u0 < 40) {
                    #pragma unroll
                    for (int nt = 0; nt < 3; ++nt) {
                        int v = nt * 16 + m;
                        if (v < 40) {
                            #pragma unroll
                            for (int g = 0; g < 4; ++g) {
                                float2 o;
                                o.x = fmaxf(accR[mt][nt][g] * 0.025f, 0.f);
                                o.y = fmaxf(accI[mt][nt][g] * 0.025f, 0.f);
                                As[(u0 + g) * ST + v] = o;
                            }
                        }
                    }
                }
            }
            // re-zero pad rows 40..47 (T-plane overlay corrupted them)
            #pragma unroll
            for (int c = 0; c < 3; ++c) {
                int idx = c * 64 + lane;
                int r = 40 + idx / 24, w2 = (idx - (idx / 24) * 24) * 2;
                *(float4*)&As[r * ST + w2] = make_float4(0.f, 0.f, 0.f, 0.f);
            }
            __syncthreads();
        } else {
            // final: scale, store to global
            float2* dst = outg + base;
            #pragma unroll
            for (int mt = 0; mt < 3; ++mt) {
                int u0 = mt * 16 + q * 4;
                if (u0 < 40) {
                    #pragma unroll
                    for (int nt = 0; nt < 3; ++nt) {
                        int v = nt * 16 + m;
                        if (v < 40) {
                            #pragma unroll
                            for (int g = 0; g < 4; ++g) {
                                float2 o;
                                o.x = accR[mt][nt][g] * 0.025f;
                                o.y = accI[mt][nt][g] * 0.025f;
                                dst[(u0 + g) * NIMG + v] = o;
                            }
                        }
                    }
                }
            }
        }
    }
}

// ---------------------------------------------------------------------------
// Per-frequency channel mix (unchanged): M[b][o][f] = sum_i F[b][i][f]*W[i][o][f]
// ---------------------------------------------------------------------------
template<int INC, int OUTC, int BT, int OT>
__global__ __launch_bounds__(256) void mix_kernel(const float2* __restrict__ F,
                                                  const float2* __restrict__ W,
                                                  float2* __restrict__ M)
{
    const int tid = threadIdx.x;
    const int lane = tid & 63;
    const int wv = tid >> 6;
    const int f = (blockIdx.x % 25) * 64 + lane;
    const int bg = (blockIdx.x / 25) * 4 + wv;
    const int b0 = bg * BT;

    #pragma unroll
    for (int o0 = 0; o0 < OUTC; o0 += OT) {
        float2 acc[BT][OT];
        #pragma unroll
        for (int t = 0; t < BT; ++t)
            #pragma unroll
            for (int o = 0; o < OT; ++o)
                acc[t][o] = make_float2(0.0f, 0.0f);

        for (int i = 0; i < INC; ++i) {
            float2 fv[BT];
            #pragma unroll
            for (int t = 0; t < BT; ++t)
                fv[t] = F[((size_t)(b0 + t) * INC + i) * NPIX + f];
            float2 wr[OT];
            #pragma unroll
            for (int o = 0; o < OT; ++o)
                wr[o] = W[((size_t)i * OUTC + (o0 + o)) * NPIX + f];
            #pragma unroll
            for (int t = 0; t < BT; ++t)
                #pragma unroll
                for (int o = 0; o < OT; ++o)
                    cfma(acc[t][o], fv[t].x, fv[t].y, wr[o].x, wr[o].y);
        }
        #pragma unroll
        for (int t = 0; t < BT; ++t)
            #pragma unroll
            for (int o = 0; o < OT; ++o)
                M[((size_t)(b0 + t) * OUTC + (o0 + o)) * NPIX + f] = acc[t][o];
    }
}

extern "C" void kernel_launch(void* const* d_in, const int* in_sizes, int n_in,
                              void* d_out, int out_size, void* d_ws, size_t ws_size,
                              hipStream_t stream)
{
    const float* x = (const float*)d_in[0];
    const float2* w[6];
    for (int i = 0; i < 6; ++i) w[i] = (const float2*)d_in[1 + i];
    float* out = (float*)d_out;

    const size_t bufBytes = (size_t)256 * 40 * NPIX * sizeof(float2);  // 131.072 MB
    float2* A = (float2*)d_ws;
    float2* B = (float2*)((char*)d_ws + bufBytes);
    unsigned short* Dtab = (unsigned short*)((char*)d_ws + 2 * bufBytes);  // 36864 B

    const int FUSEBLK = 256 * 40;              // one wave per image
    const int MIXBLK = 25 * (256 / 4) / 4;     // 400

    init_dtab<<<9, 256, 0, stream>>>(Dtab);

    // L1 head: fft(x) (small, 256 images)
    fft2_kernel<true, false, false><<<256, 256, 0, stream>>>(x, A, -1);

    // mix_l -> fused(ifft+relu+fft) for layers 1..5
    mix_kernel<1, 40, 4, 10><<<MIXBLK, 256, 0, stream>>>(A, w[0], B);
    fused_mfma_kernel<<<FUSEBLK, 64, 0, stream>>>(B, A, Dtab);
    for (int l = 1; l <= 4; ++l) {
        mix_kernel<40, 40, 4, 10><<<MIXBLK, 256, 0, stream>>>(A, w[l], B);
        fused_mfma_kernel<<<FUSEBLK, 64, 0, stream>>>(B, A, Dtab);
    }

    // L6: mix(40->1) then final ifft (small, 256 images), real output
    mix_kernel<40, 1, 4, 1><<<MIXBLK, 256, 0, stream>>>(A, w[5], B);
    fft2_kernel<false, false, true><<<256, 256, 0, stream>>>(B, out, +1);
}